// Round 1
// baseline (29.365 us; speedup 1.0000x reference)
//
#include <hip/hip_runtime.h>

#define HEAD_DIM   128
#define HIDDEN     2048
#define MAX_SEQ    2048
#define NUM_HEADS  16
#define NUM_KV     8
#define LAYER_IDX  5
#define NSPLIT     64
#define CHUNK      (MAX_SEQ / NSPLIT)   // 32
#define SCALE      0.08838834764831845f // 1/sqrt(128)

// ws layout (floats)
#define WS_Q     0        // 2048
#define WS_K     2048     // 1024
#define WS_V     3072     // 1024
#define WS_M     4096     // 16*64
#define WS_L     5120     // 16*64
#define WS_O     6144     // 16*64*128
#define WS_ATTN  137216   // 2048

__device__ __forceinline__ float wave_reduce_sum(float v) {
    #pragma unroll
    for (int off = 32; off > 0; off >>= 1) v += __shfl_xor(v, off);
    return v;
}

// ---------------- Kernel 1: q/k/v projections (row-per-block matvec) ----------------
__global__ __launch_bounds__(256) void qkv_kernel(const float* __restrict__ x,
                                                  const float* __restrict__ q_w,
                                                  const float* __restrict__ k_w,
                                                  const float* __restrict__ v_w,
                                                  float* __restrict__ ws) {
    const int row = blockIdx.x;  // 0..4095
    const float* w;
    float* out;
    if (row < 2048)      { w = q_w + (size_t)row * HIDDEN;          out = ws + WS_Q + row; }
    else if (row < 3072) { w = k_w + (size_t)(row - 2048) * HIDDEN; out = ws + WS_K + (row - 2048); }
    else                 { w = v_w + (size_t)(row - 3072) * HIDDEN; out = ws + WS_V + (row - 3072); }
    const int t = threadIdx.x;
    float4 a0 = ((const float4*)w)[t];
    float4 a1 = ((const float4*)w)[t + 256];
    float4 x0 = ((const float4*)x)[t];
    float4 x1 = ((const float4*)x)[t + 256];
    float p = a0.x * x0.x + a0.y * x0.y + a0.z * x0.z + a0.w * x0.w
            + a1.x * x1.x + a1.y * x1.y + a1.z * x1.z + a1.w * x1.w;
    p = wave_reduce_sum(p);
    __shared__ float red[4];
    if ((t & 63) == 0) red[t >> 6] = p;
    __syncthreads();
    if (t == 0) *out = red[0] + red[1] + red[2] + red[3];
}

// ---------------- Kernel 2: flash-decode partials, one block per (kv-head, split) ----
__global__ __launch_bounds__(256) void attn_partial_kernel(const float* __restrict__ kv_cache,
                                                           const float* __restrict__ ws_qkv,
                                                           const int* __restrict__ cur_pos,
                                                           float* __restrict__ m_part,
                                                           float* __restrict__ l_part,
                                                           float* __restrict__ o_part) {
    const int g     = blockIdx.x;      // kv head
    const int split = blockIdx.y;      // 0..NSPLIT-1
    const int s0    = split * CHUNK;
    const int cpos  = *cur_pos;
    const int t     = threadIdx.x;
    const int wave  = t >> 6, lane = t & 63;

    const float* kbase = kv_cache + ((size_t)(2 * LAYER_IDX)     * NUM_KV + g) * (size_t)MAX_SEQ * HEAD_DIM;
    const float* vbase = kv_cache + ((size_t)(2 * LAYER_IDX + 1) * NUM_KV + g) * (size_t)MAX_SEQ * HEAD_DIM;
    const float* knew  = ws_qkv + WS_K + g * HEAD_DIM;
    const float* vnew  = ws_qkv + WS_V + g * HEAD_DIM;
    const float* q0    = ws_qkv + WS_Q + (g * 2 + 0) * HEAD_DIM;
    const float* q1    = ws_qkv + WS_Q + (g * 2 + 1) * HEAD_DIM;

    __shared__ float sc[2][CHUNK];
    __shared__ float ee[2][CHUNK];
    __shared__ float ml[2][2];  // [rep][0]=m, [rep][1]=l

    // ---- score phase: each wave computes CHUNK/4 positions, lanes split d ----
    float2 q0v = *(const float2*)(q0 + lane * 2);
    float2 q1v = *(const float2*)(q1 + lane * 2);
    #pragma unroll
    for (int i = 0; i < CHUNK / 4; ++i) {
        int j = wave * (CHUNK / 4) + i;
        int s = s0 + j;
        const float* krow = (s == cpos) ? knew : (kbase + (size_t)s * HEAD_DIM);
        float2 kk = *(const float2*)(krow + lane * 2);
        float d0 = q0v.x * kk.x + q0v.y * kk.y;
        float d1 = q1v.x * kk.x + q1v.y * kk.y;
        d0 = wave_reduce_sum(d0);
        d1 = wave_reduce_sum(d1);
        if (lane == 0) { sc[0][j] = d0 * SCALE; sc[1][j] = d1 * SCALE; }
    }
    __syncthreads();

    // ---- per-rep serial softmax partial (tiny: 32 values) ----
    if (t < 2) {
        float m = -1e30f;
        for (int j = 0; j < CHUNK; ++j) m = fmaxf(m, sc[t][j]);
        float l = 0.f;
        for (int j = 0; j < CHUNK; ++j) { float e = __expf(sc[t][j] - m); ee[t][j] = e; l += e; }
        ml[t][0] = m; ml[t][1] = l;
    }
    __syncthreads();

    // ---- O accumulation: thread -> (rep, d) ----
    const int rep = t >> 7, d = t & 127;
    float acc = 0.f;
    #pragma unroll 4
    for (int j = 0; j < CHUNK; ++j) {
        int s = s0 + j;
        const float* vrow = (s == cpos) ? vnew : (vbase + (size_t)s * HEAD_DIM);
        acc += ee[rep][j] * vrow[d];
    }
    const int h = g * 2 + rep;
    o_part[((size_t)h * NSPLIT + split) * HEAD_DIM + d] = acc;
    if (d == 0) {
        m_part[h * NSPLIT + split] = ml[rep][0];
        l_part[h * NSPLIT + split] = ml[rep][1];
    }
}

// ---------------- Kernel 3: combine partials into attn ----------------
__global__ __launch_bounds__(128) void combine_kernel(const float* __restrict__ m_part,
                                                      const float* __restrict__ l_part,
                                                      const float* __restrict__ o_part,
                                                      float* __restrict__ attn) {
    const int h = blockIdx.x;
    const int t = threadIdx.x;
    __shared__ float wsc[NSPLIT];
    __shared__ float Linv_s;
    if (t < 64) {
        float m = m_part[h * NSPLIT + t];
        float M = m;
        #pragma unroll
        for (int off = 32; off > 0; off >>= 1) M = fmaxf(M, __shfl_xor(M, off));
        float w = __expf(m - M);
        wsc[t] = w;
        float L = wave_reduce_sum(l_part[h * NSPLIT + t] * w);
        if (t == 0) Linv_s = 1.0f / L;
    }
    __syncthreads();
    float acc = 0.f;
    #pragma unroll 8
    for (int i = 0; i < NSPLIT; ++i)
        acc += o_part[((size_t)h * NSPLIT + i) * HEAD_DIM + t] * wsc[i];
    attn[h * HEAD_DIM + t] = acc * Linv_s;
}

// ---------------- Kernel 4: output projection ----------------
__global__ __launch_bounds__(256) void out_kernel(const float* __restrict__ o_w,
                                                  const float* __restrict__ attn,
                                                  float* __restrict__ out) {
    const int row = blockIdx.x;
    const float* w = o_w + (size_t)row * HIDDEN;
    const int t = threadIdx.x;
    float4 a0 = ((const float4*)w)[t];
    float4 a1 = ((const float4*)w)[t + 256];
    float4 x0 = ((const float4*)attn)[t];
    float4 x1 = ((const float4*)attn)[t + 256];
    float p = a0.x * x0.x + a0.y * x0.y + a0.z * x0.z + a0.w * x0.w
            + a1.x * x1.x + a1.y * x1.y + a1.z * x1.z + a1.w * x1.w;
    p = wave_reduce_sum(p);
    __shared__ float red[4];
    if ((t & 63) == 0) red[t >> 6] = p;
    __syncthreads();
    if (t == 0) out[row] = red[0] + red[1] + red[2] + red[3];
}

extern "C" void kernel_launch(void* const* d_in, const int* in_sizes, int n_in,
                              void* d_out, int out_size, void* d_ws, size_t ws_size,
                              hipStream_t stream) {
    const float* x    = (const float*)d_in[0];
    const float* kv   = (const float*)d_in[1];
    const float* q_w  = (const float*)d_in[2];
    const float* k_w  = (const float*)d_in[3];
    const float* v_w  = (const float*)d_in[4];
    const float* o_w  = (const float*)d_in[5];
    const int*   cpos = (const int*)d_in[6];
    float* ws  = (float*)d_ws;
    float* out = (float*)d_out;

    qkv_kernel<<<4096, 256, 0, stream>>>(x, q_w, k_w, v_w, ws);
    attn_partial_kernel<<<dim3(NUM_KV, NSPLIT), 256, 0, stream>>>(
        kv, ws, cpos, ws + WS_M, ws + WS_L, ws + WS_O);
    combine_kernel<<<NUM_HEADS, 128, 0, stream>>>(ws + WS_M, ws + WS_L, ws + WS_O, ws + WS_ATTN);
    out_kernel<<<HIDDEN, 256, 0, stream>>>(o_w, ws + WS_ATTN, out);
}